// Round 5
// baseline (24.540 us; speedup 1.0000x reference)
//
#include <hip/hip_runtime.h>

#define TBLSZ 4096
#define NSIZES 18
#define DIM 256
#define D4 (DIM / 4)        // float4s per position
#define SEQLEN 8192
#define INV19 (1.0f / 19.0f)
#define CHUNK 64            // positions per ballot-chunk
#define WPC 2               // waves cooperating per chunk
#define SLICE (CHUNK / WPC) // 32 positions stored per wave
#define CPB 2               // chunks per block (256 thr = 4 waves = 2 chunks)

typedef float f32x4 __attribute__((ext_vector_type(4)));

__global__ __launch_bounds__(256) void NGramEmbedding_73718818668652_kernel(
    const int* __restrict__ byte_ids, const float* __restrict__ tables,
    f32x4* __restrict__ out)
{
    __shared__ f32x4 s_part[4][64];

    const int lane = threadIdx.x & 63;
    const int wv   = threadIdx.x >> 6;          // 0..3
    const f32x4* T4base = (const f32x4*)tables;

    // Cooperative smix: each wave sums 4-5 mixed rows; LDS-reduce; pre-scaled.
    f32x4 part = {0.f, 0.f, 0.f, 0.f};
    for (int t = wv; t < NSIZES; t += 4)
        part += T4base[((size_t)t * (TBLSZ + 1) + TBLSZ) * D4 + lane];
    s_part[wv][lane] = part;
    __syncthreads();
    const f32x4 base = (s_part[0][lane] + s_part[1][lane] +
                        s_part[2][lane] + s_part[3][lane]) * INV19;

    // This wave's chunk (64 positions, shared with one sibling wave) and slice.
    const int cid       = blockIdx.x * CPB + (wv >> 1);
    const int sub       = wv & 1;
    const int chunkBase = cid * CHUNK;
    const int ibase     = chunkBase & (SEQLEN - 1);   // rows are 64-aligned
    const int* row      = byte_ids + (chunkBase - ibase);

    // Lane l checks position chunkBase+l: size-3 window all-DNA?
    const int i = ibase + lane;
    bool slowb = false;
    if (i >= 2) {
        const int v0 = row[i], v1 = row[i - 1], v2 = row[i - 2];
        slowb = ((unsigned)(v0 - 1) < 4u) & ((unsigned)(v1 - 1) < 4u)
              & ((unsigned)(v2 - 1) < 4u);
    }
    const unsigned long long mask = __ballot(slowb);

    const int p0 = sub * SLICE;
    f32x4* dst = out + (size_t)(chunkBase + p0) * D4 + lane;

    if (((mask >> p0) & 0xFFFFFFFFull) == 0) {
        // Pure fast path: 32 back-to-back nontemporal 1KB stores.
#pragma unroll
        for (int p = 0; p < SLICE; ++p)
            __builtin_nontemporal_store(base, &dst[(size_t)p * D4]);
    } else {
        for (int p = 0; p < SLICE; ++p) {
            f32x4 r = base;
            if ((mask >> (p0 + p)) & 1ull) {          // wave-uniform, rare
                const int ii = ibase + p0 + p;
                f32x4 acc = {0.f, 0.f, 0.f, 0.f};
                int h = 0, pw = 1;
                for (int j = 0; j < 20; ++j) {
                    const int q = ii - j;
                    const int v = (q >= 0) ? row[q] : 0;
                    if ((unsigned)(v - 1) >= 4u) break;   // window bad beyond here
                    h  = (h + (v - 1) * pw) & (TBLSZ - 1);
                    pw = (pw * 31) & (TBLSZ - 1);
                    const int k = j + 1;
                    if (k >= 3) {
                        const f32x4* T4 = T4base + (size_t)(k - 3) * (TBLSZ + 1) * D4;
                        const f32x4 g = T4[(size_t)h * D4 + lane];
                        const f32x4 m = T4[(size_t)TBLSZ * D4 + lane];
                        acc += g - m;
                    }
                }
                r += acc * INV19;
            }
            __builtin_nontemporal_store(r, &dst[(size_t)p * D4]);
        }
    }
}

extern "C" void kernel_launch(void* const* d_in, const int* in_sizes, int n_in,
                              void* d_out, int out_size, void* d_ws, size_t ws_size,
                              hipStream_t stream) {
    const int*   byte_ids = (const int*)d_in[0];
    const float* tables   = (const float*)d_in[1];
    float* out = (float*)d_out;
    const int npos    = in_sizes[0];              // B*L = 65536
    const int nblocks = npos / (CHUNK * CPB);     // 512

    hipLaunchKernelGGL(NGramEmbedding_73718818668652_kernel,
                       dim3(nblocks), dim3(256), 0, stream,
                       byte_ids, tables, (f32x4*)out);
}

// Round 6
// 24.174 us; speedup vs baseline: 1.0152x; 1.0152x over previous
//
#include <hip/hip_runtime.h>

#define TBLSZ 4096
#define NSIZES 18
#define DIM 256
#define D4 (DIM / 4)        // float4s per position
#define SEQLEN 8192
#define INV19 (1.0f / 19.0f)
#define CHUNK 64            // positions per block
#define WPC 4               // waves per block
#define SLICE (CHUNK / WPC) // 16 positions stored per wave

typedef float f32x4 __attribute__((ext_vector_type(4)));

__global__ __launch_bounds__(256) void NGramEmbedding_73718818668652_kernel(
    const int* __restrict__ byte_ids, const float* __restrict__ tables,
    f32x4* __restrict__ out)
{
    __shared__ f32x4 s_part[WPC][64];

    const int lane = threadIdx.x & 63;
    const int wv   = threadIdx.x >> 6;
    const int cid  = blockIdx.x;

    const f32x4* T4base = (const f32x4*)tables;

    // Cooperative smix (sum of 18 mixed rows, pre-scaled by 1/19): 18 KB per block.
    f32x4 part = {0.f, 0.f, 0.f, 0.f};
    for (int t = wv; t < NSIZES; t += WPC)
        part += T4base[((size_t)t * (TBLSZ + 1) + TBLSZ) * D4 + lane];
    s_part[wv][lane] = part;
    __syncthreads();
    const f32x4 base = (s_part[0][lane] + s_part[1][lane] +
                        s_part[2][lane] + s_part[3][lane]) * INV19;

    const int chunkBase = cid * CHUNK;
    const int ibase     = chunkBase & (SEQLEN - 1);  // rows are 64-aligned
    const int* row      = byte_ids + (chunkBase - ibase);

    // Lane l checks position chunkBase+l: size-3 window all-DNA?
    const int i = ibase + lane;
    bool slowb = false;
    if (i >= 2) {
        const int v0 = row[i], v1 = row[i - 1], v2 = row[i - 2];
        slowb = ((unsigned)(v0 - 1) < 4u) & ((unsigned)(v1 - 1) < 4u)
              & ((unsigned)(v2 - 1) < 4u);
    }
    const unsigned long long mask = __ballot(slowb);

    const int p0 = wv * SLICE;
    f32x4* dst = out + (size_t)(chunkBase + p0) * D4 + lane;

    if (((mask >> p0) & 0xFFFFull) == 0) {
        // Pure fast path: 16 back-to-back cached 1KB stores (L3 can absorb
        // the 64MB output across graph replays; NT stores forfeited that).
#pragma unroll
        for (int p = 0; p < SLICE; ++p)
            dst[(size_t)p * D4] = base;
    } else {
        for (int p = 0; p < SLICE; ++p) {
            f32x4 r = base;
            if ((mask >> (p0 + p)) & 1ull) {          // wave-uniform, rare
                const int ii = ibase + p0 + p;
                f32x4 acc = {0.f, 0.f, 0.f, 0.f};
                int h = 0, pw = 1;
                for (int j = 0; j < 20; ++j) {
                    const int q = ii - j;
                    const int v = (q >= 0) ? row[q] : 0;
                    if ((unsigned)(v - 1) >= 4u) break;   // window bad beyond here
                    h  = (h + (v - 1) * pw) & (TBLSZ - 1);
                    pw = (pw * 31) & (TBLSZ - 1);
                    const int k = j + 1;
                    if (k >= 3) {
                        const f32x4* T4 = T4base + (size_t)(k - 3) * (TBLSZ + 1) * D4;
                        const f32x4 g = T4[(size_t)h * D4 + lane];
                        const f32x4 m = T4[(size_t)TBLSZ * D4 + lane];
                        acc += g - m;
                    }
                }
                r += acc * INV19;
            }
            dst[(size_t)p * D4] = r;
        }
    }
}

extern "C" void kernel_launch(void* const* d_in, const int* in_sizes, int n_in,
                              void* d_out, int out_size, void* d_ws, size_t ws_size,
                              hipStream_t stream) {
    const int*   byte_ids = (const int*)d_in[0];
    const float* tables   = (const float*)d_in[1];
    float* out = (float*)d_out;
    const int npos   = in_sizes[0];          // B*L = 65536
    const int nchunk = npos / CHUNK;         // 1024

    hipLaunchKernelGGL(NGramEmbedding_73718818668652_kernel,
                       dim3(nchunk), dim3(256), 0, stream,
                       byte_ids, tables, (f32x4*)out);
}

// Round 7
// 21.852 us; speedup vs baseline: 1.1230x; 1.1062x over previous
//
#include <hip/hip_runtime.h>

#define TBLSZ 4096
#define NSIZES 18
#define DIM 256
#define D4 (DIM / 4)        // float4s per position
#define SEQLEN 8192
#define INV19 (1.0f / 19.0f)
#define CHUNK 64            // positions per block
#define WPC 4               // waves per block
#define SLICE (CHUNK / WPC) // 16 positions stored per wave

typedef float f32x4 __attribute__((ext_vector_type(4)));

__global__ __launch_bounds__(256) void NGramEmbedding_73718818668652_kernel(
    const int* __restrict__ byte_ids, const float* __restrict__ tables,
    f32x4* __restrict__ out)
{
    __shared__ f32x4 s_part[WPC][64];

    const int lane = threadIdx.x & 63;
    const int wv   = threadIdx.x >> 6;
    const int cid  = blockIdx.x;

    const f32x4* T4base = (const f32x4*)tables;

    // Cooperative smix (sum of 18 mixed rows, pre-scaled by 1/19): 18 KB per block.
    f32x4 part = {0.f, 0.f, 0.f, 0.f};
    for (int t = wv; t < NSIZES; t += WPC)
        part += T4base[((size_t)t * (TBLSZ + 1) + TBLSZ) * D4 + lane];
    s_part[wv][lane] = part;
    __syncthreads();
    const f32x4 base = (s_part[0][lane] + s_part[1][lane] +
                        s_part[2][lane] + s_part[3][lane]) * INV19;

    const int chunkBase = cid * CHUNK;
    const int ibase     = chunkBase & (SEQLEN - 1);  // rows are 64-aligned
    const int* row      = byte_ids + (chunkBase - ibase);

    // Lane l checks position chunkBase+l: size-3 window all-DNA?
    const int i = ibase + lane;
    bool slowb = false;
    if (i >= 2) {
        const int v0 = row[i], v1 = row[i - 1], v2 = row[i - 2];
        slowb = ((unsigned)(v0 - 1) < 4u) & ((unsigned)(v1 - 1) < 4u)
              & ((unsigned)(v2 - 1) < 4u);
    }
    const unsigned long long mask = __ballot(slowb);

    const int p0 = wv * SLICE;
    f32x4* dst = out + (size_t)(chunkBase + p0) * D4 + lane;

    if (((mask >> p0) & 0xFFFFull) == 0) {
        // Pure fast path: 16 back-to-back nontemporal 1KB stores
        // (measured best: NT beats cached stores 22.1 vs 24.2 µs).
#pragma unroll
        for (int p = 0; p < SLICE; ++p)
            __builtin_nontemporal_store(base, &dst[(size_t)p * D4]);
    } else {
        for (int p = 0; p < SLICE; ++p) {
            f32x4 r = base;
            if ((mask >> (p0 + p)) & 1ull) {          // wave-uniform, rare
                const int ii = ibase + p0 + p;
                f32x4 acc = {0.f, 0.f, 0.f, 0.f};
                int h = 0, pw = 1;
                for (int j = 0; j < 20; ++j) {
                    const int q = ii - j;
                    const int v = (q >= 0) ? row[q] : 0;
                    if ((unsigned)(v - 1) >= 4u) break;   // window bad beyond here
                    h  = (h + (v - 1) * pw) & (TBLSZ - 1);
                    pw = (pw * 31) & (TBLSZ - 1);
                    const int k = j + 1;
                    if (k >= 3) {
                        const f32x4* T4 = T4base + (size_t)(k - 3) * (TBLSZ + 1) * D4;
                        const f32x4 g = T4[(size_t)h * D4 + lane];
                        const f32x4 m = T4[(size_t)TBLSZ * D4 + lane];
                        acc += g - m;
                    }
                }
                r += acc * INV19;
            }
            __builtin_nontemporal_store(r, &dst[(size_t)p * D4]);
        }
    }
}

extern "C" void kernel_launch(void* const* d_in, const int* in_sizes, int n_in,
                              void* d_out, int out_size, void* d_ws, size_t ws_size,
                              hipStream_t stream) {
    const int*   byte_ids = (const int*)d_in[0];
    const float* tables   = (const float*)d_in[1];
    float* out = (float*)d_out;
    const int npos   = in_sizes[0];          // B*L = 65536
    const int nchunk = npos / CHUNK;         // 1024

    hipLaunchKernelGGL(NGramEmbedding_73718818668652_kernel,
                       dim3(nchunk), dim3(256), 0, stream,
                       byte_ids, tables, (f32x4*)out);
}